// Round 6
// baseline (1029.558 us; speedup 1.0000x reference)
//
#include <hip/hip_runtime.h>
#include <stdint.h>

typedef __bf16 bf16x8 __attribute__((ext_vector_type(8)));
typedef float f32x4 __attribute__((ext_vector_type(4)));

#define LOG2E 1.4426950408889634f
#define LSTR 32  // LDS row stride in shorts (64 B); required by global_load_lds scatter

__device__ __forceinline__ unsigned short f2bf(float f) {
  unsigned int x = __builtin_bit_cast(unsigned int, f);
  x += 0x7FFFu + ((x >> 16) & 1u);
  return (unsigned short)(x >> 16);
}
__device__ __forceinline__ float bflo(unsigned int u) {
  return __builtin_bit_cast(float, u << 16);
}
__device__ __forceinline__ float bfhi(unsigned int u) {
  return __builtin_bit_cast(float, u & 0xffff0000u);
}
__device__ __forceinline__ float tanh_fast(float x) {
  float cx = fminf(fmaxf(x, -15.f), 15.f);
  float e = __builtin_amdgcn_exp2f(cx * (2.f * LOG2E));   // e^(2x)
  return (e - 1.f) * __builtin_amdgcn_rcpf(e + 1.f);
}
__device__ __forceinline__ float sigmoid_fast(float x) {
  float cx = fminf(fmaxf(x, -30.f), 30.f);
  float e = __builtin_amdgcn_exp2f(cx * LOG2E);           // e^x
  return e * __builtin_amdgcn_rcpf(e + 1.f);
}
__device__ __forceinline__ ushort4 cvt4(const float4 f) {
  return make_ushort4(f2bf(f.x), f2bf(f.y), f2bf(f.z), f2bf(f.w));
}

// async global->LDS, 16B/lane; LDS dest = wave-uniform base + lane*16.
__device__ __forceinline__ void gl_lds16(const unsigned short* g,
                                         const unsigned short* lds_base) {
  __builtin_amdgcn_global_load_lds(
      (const __attribute__((address_space(1))) unsigned int*)(uintptr_t)g,
      (__attribute__((address_space(3))) unsigned int*)(unsigned int)(uintptr_t)lds_base,
      16, 0, 0);
}

// ---------------------------------------------------------------------------
// 0) Fused prep: [0,256) W_enc transpose->bf16 | [256,768) dvec |
//    [768,1248) zero scoresb/att/gbuf | [1248,17632) enc fp32->bf16
// ---------------------------------------------------------------------------
__global__ __launch_bounds__(256) void k_prep(
    const float* __restrict__ W_enc, unsigned short* __restrict__ Wt,
    const float* __restrict__ states, const float* __restrict__ W_dec,
    const float* __restrict__ b_dec, const float* __restrict__ b_enc,
    float* __restrict__ dvec, float4* __restrict__ zbase,
    const float* __restrict__ enc, unsigned short* __restrict__ encb) {
  __shared__ unsigned short tile[64][65];
  __shared__ float red[256];
  const int bid = blockIdx.x;
  const int tid = threadIdx.x;
  if (bid < 256) {            // ---- transpose W_enc -> Wt (bf16)
    const int bx = bid & 15, by = bid >> 4;
    const int x = tid & 63, y0 = tid >> 6;
#pragma unroll
    for (int i = y0; i < 64; i += 4)
      tile[i][x] = f2bf(W_enc[(size_t)(by * 64 + i) * 1024 + bx * 64 + x]);
    __syncthreads();
#pragma unroll
    for (int i = y0; i < 64; i += 4)
      Wt[(size_t)(bx * 64 + i) * 1024 + by * 64 + x] = tile[x][i];
  } else if (bid < 768) {     // ---- dvec
    const int bb = bid - 256;
    const int b = bb >> 3;
    const int a0 = (bb & 7) * 128;
    const int a = tid & 127, half = tid >> 7;
    const float* sp = states + (size_t)b * 1024;
    const float* wp = W_dec + a0 + a;
    float acc = 0.f;
    const int kb = half * 512;
#pragma unroll 8
    for (int k = kb; k < kb + 512; ++k)
      acc += sp[k] * wp[(size_t)k * 1024];
    red[tid] = acc;
    __syncthreads();
    if (tid < 128) {
      float v = red[tid] + red[tid + 128];
      dvec[(size_t)b * 1024 + a0 + tid] = v + b_dec[a0 + tid] + b_enc[a0 + tid];
    }
  } else if (bid < 1248) {    // ---- zero 1.92 MB (scoresb|att|gbuf)
    const float4 z = {0.f, 0.f, 0.f, 0.f};
    zbase[(size_t)(bid - 768) * 256 + tid] = z;
  } else {                    // ---- enc fp32 -> bf16
    const size_t i = ((size_t)(bid - 1248) * 256 + tid) * 8;
    const float4 f0 = *(const float4*)(enc + i);
    const float4 f1 = *(const float4*)(enc + i + 4);
    *(ushort4*)(encb + i) = cvt4(f0);
    *(ushort4*)(encb + i + 4) = cvt4(f1);
  }
}

// ---------------------------------------------------------------------------
// 3a) Fused scores, bf16 fast path. Grid = 256 M-tiles x 4 N-halves = 1024.
//     Both N-tiles of the half processed in ONE K-sweep (acc[2]); staging
//     via global_load_lds (24 regions: 8 lA + 16 lB across 4 waves).
// ---------------------------------------------------------------------------
__global__ __launch_bounds__(256) void k_scores_bf16(
    const unsigned short* __restrict__ encb,  // [32768][1024] bf16
    const unsigned short* __restrict__ Wt,    // [1024 a][1024 h] bf16
    const float* __restrict__ dvec,           // [64][1024]
    const float* __restrict__ w_out,          // [1024]
    float* __restrict__ scores) {             // [64][512], pre-zeroed
  __shared__ alignas(16) unsigned short lA[128 * LSTR];       // 8 KB
  __shared__ alignas(16) unsigned short lB[2 * 128 * LSTR];   // 16 KB
  __shared__ float sc[128];

  const int tid = threadIdx.x;
  const int wave = tid >> 6, lane = tid & 63;
  const int l15 = lane & 15, quad = lane >> 4;
  const int mt = blockIdx.x >> 2;
  const int nh = blockIdx.x & 3;
  const int row0 = mt * 128;
  const int b = row0 >> 9;
  const int wm = (wave >> 1) * 64, wn = (wave & 1) * 64;
  const int srow = lane >> 2;         // 0..15 within staging region
  const int skoff = (lane & 3) * 8;   // k element offset of 8-elem chunk

  if (tid < 128) sc[tid] = 0.f;

  const f32x4 vz = {0.f, 0.f, 0.f, 0.f};
  f32x4 acc[2][4][4];
#pragma unroll
  for (int t = 0; t < 2; ++t)
#pragma unroll
    for (int i = 0; i < 4; ++i)
#pragma unroll
      for (int j = 0; j < 4; ++j) acc[t][i][j] = vz;

#pragma unroll 1
  for (int k0 = 0; k0 < 1024; k0 += 32) {
    __syncthreads();   // prev iteration's LDS reads done
#pragma unroll
    for (int s = 0; s < 6; ++s) {   // 24 regions / 4 waves
      const int g = wave * 6 + s;
      if (g < 8) {
        gl_lds16(encb + (size_t)(row0 + g * 16 + srow) * 1024 + k0 + skoff,
                 lA + g * 512);
      } else {
        const int t = (g - 8) >> 3;        // which nt
        const int q = (g - 8) & 7;         // region within nt's B tile
        gl_lds16(Wt + (size_t)((nh * 2 + t) * 128 + q * 16 + srow) * 1024 + k0 + skoff,
                 lB + t * 4096 + q * 512);
      }
    }
    __syncthreads();   // DMA drained
    bf16x8 af[4], bg[2][4];
#pragma unroll
    for (int i = 0; i < 4; ++i)
      af[i] = *(const bf16x8*)(lA + (wm + i * 16 + l15) * LSTR + quad * 8);
#pragma unroll
    for (int t = 0; t < 2; ++t)
#pragma unroll
      for (int j = 0; j < 4; ++j)
        bg[t][j] = *(const bf16x8*)(lB + t * 4096 + (wn + j * 16 + l15) * LSTR + quad * 8);
#pragma unroll
    for (int t = 0; t < 2; ++t)
#pragma unroll
      for (int i = 0; i < 4; ++i)
#pragma unroll
        for (int j = 0; j < 4; ++j)
          acc[t][i][j] = __builtin_amdgcn_mfma_f32_16x16x32_bf16(af[i], bg[t][j],
                                                                 acc[t][i][j], 0, 0, 0);
  }

#pragma unroll 1
  for (int t = 0; t < 2; ++t) {
    const int nt = nh * 2 + t;
    float p[4][4];
#pragma unroll
    for (int i = 0; i < 4; ++i)
#pragma unroll
      for (int r = 0; r < 4; ++r) p[i][r] = 0.f;
#pragma unroll
    for (int j = 0; j < 4; ++j) {
      const int a = nt * 128 + wn + j * 16 + l15;
      const float dv = dvec[(size_t)b * 1024 + a];
      const float wo = w_out[a];
#pragma unroll
      for (int i = 0; i < 4; ++i)
#pragma unroll
        for (int r = 0; r < 4; ++r)
          p[i][r] += tanh_fast(acc[t][i][j][r] + dv) * wo;
    }
#pragma unroll
    for (int i = 0; i < 4; ++i)
#pragma unroll
      for (int r = 0; r < 4; ++r) {
        float v = p[i][r];
        v += __shfl_xor(v, 1);
        v += __shfl_xor(v, 2);
        v += __shfl_xor(v, 4);
        v += __shfl_xor(v, 8);
        if (l15 == 0) atomicAdd(&sc[wm + i * 16 + quad * 4 + r], v);
      }
  }
  __syncthreads();
  if (tid < 128)
    atomicAdd(&scores[(size_t)b * 512 + (row0 & 511) + tid], sc[tid]);
}

// ---------------------------------------------------------------------------
// 3b) fp32 fallback (round-5 structure, manual staging)
// ---------------------------------------------------------------------------
__global__ __launch_bounds__(256) void k_scores_f32(
    const float* __restrict__ enc, const unsigned short* __restrict__ Wt,
    const float* __restrict__ dvec, const float* __restrict__ w_out,
    float* __restrict__ scores) {
  __shared__ alignas(16) unsigned short lA[128 * LSTR];
  __shared__ alignas(16) unsigned short lB[128 * LSTR];
  __shared__ float sc[128];
  const int tid = threadIdx.x;
  const int wave = tid >> 6, lane = tid & 63;
  const int l15 = lane & 15, quad = lane >> 4;
  const int mt = blockIdx.x >> 2, nh = blockIdx.x & 3;
  const int row0 = mt * 128, b = row0 >> 9;
  const int wm = (wave >> 1) * 64, wn = (wave & 1) * 64;
  const int srow = lane >> 2, skoff = (lane & 3) * 8;
  if (tid < 128) sc[tid] = 0.f;
  const f32x4 vz = {0.f, 0.f, 0.f, 0.f};
#pragma unroll 1
  for (int t2 = 0; t2 < 2; ++t2) {
    const int nt = nh * 2 + t2;
    f32x4 acc[4][4];
#pragma unroll
    for (int i = 0; i < 4; ++i)
#pragma unroll
      for (int j = 0; j < 4; ++j) acc[i][j] = vz;
#pragma unroll 1
    for (int k0 = 0; k0 < 1024; k0 += 32) {
      ushort4 sa[2][2];
      uint4 vb[2];
#pragma unroll
      for (int rr = 0; rr < 2; ++rr) {
        const int r = wave * 2 + rr;
        const float* ap = enc + (size_t)(row0 + r * 16 + srow) * 1024 + k0 + skoff;
        sa[rr][0] = cvt4(*(const float4*)ap);
        sa[rr][1] = cvt4(*(const float4*)(ap + 4));
        vb[rr] = *(const uint4*)(Wt + (size_t)(nt * 128 + r * 16 + srow) * 1024 + k0 + skoff);
      }
      __syncthreads();
#pragma unroll
      for (int rr = 0; rr < 2; ++rr) {
        const int r = wave * 2 + rr;
        *(ushort4*)(lA + (r * 16 + srow) * LSTR + skoff) = sa[rr][0];
        *(ushort4*)(lA + (r * 16 + srow) * LSTR + skoff + 4) = sa[rr][1];
        *(uint4*)(lB + (r * 16 + srow) * LSTR + skoff) = vb[rr];
      }
      __syncthreads();
      bf16x8 af[4], bg[4];
#pragma unroll
      for (int i = 0; i < 4; ++i)
        af[i] = *(const bf16x8*)(lA + (wm + i * 16 + l15) * LSTR + quad * 8);
#pragma unroll
      for (int j = 0; j < 4; ++j)
        bg[j] = *(const bf16x8*)(lB + (wn + j * 16 + l15) * LSTR + quad * 8);
#pragma unroll
      for (int i = 0; i < 4; ++i)
#pragma unroll
        for (int j = 0; j < 4; ++j)
          acc[i][j] = __builtin_amdgcn_mfma_f32_16x16x32_bf16(af[i], bg[j],
                                                              acc[i][j], 0, 0, 0);
    }
    float p[4][4];
#pragma unroll
    for (int i = 0; i < 4; ++i)
#pragma unroll
      for (int r = 0; r < 4; ++r) p[i][r] = 0.f;
#pragma unroll
    for (int j = 0; j < 4; ++j) {
      const int a = nt * 128 + wn + j * 16 + l15;
      const float dv = dvec[(size_t)b * 1024 + a];
      const float wo = w_out[a];
#pragma unroll
      for (int i = 0; i < 4; ++i)
#pragma unroll
        for (int r = 0; r < 4; ++r)
          p[i][r] += tanh_fast(acc[i][j][r] + dv) * wo;
    }
#pragma unroll
    for (int i = 0; i < 4; ++i)
#pragma unroll
      for (int r = 0; r < 4; ++r) {
        float v = p[i][r];
        v += __shfl_xor(v, 1);
        v += __shfl_xor(v, 2);
        v += __shfl_xor(v, 4);
        v += __shfl_xor(v, 8);
        if (l15 == 0) atomicAdd(&sc[wm + i * 16 + quad * 4 + r], v);
      }
  }
  __syncthreads();
  if (tid < 128)
    atomicAdd(&scores[(size_t)b * 512 + (row0 & 511) + tid], sc[tid]);
}

// ---------------------------------------------------------------------------
// 4) softmax over S + weighted sum of encoded -> att (fp32, atomic)
// ---------------------------------------------------------------------------
template <bool ABF16>
__global__ __launch_bounds__(256) void k_attn(const void* __restrict__ encv,
                                              const float* __restrict__ scores,
                                              float* __restrict__ att) {
  const int b = blockIdx.x >> 2;
  const int scn = blockIdx.x & 3;
  const int tid = threadIdx.x;
  __shared__ float w[512];
  __shared__ float redm[4], reds[4];

  const float s0 = scores[(size_t)b * 512 + tid];
  const float s1 = scores[(size_t)b * 512 + 256 + tid];
  float m = fmaxf(s0, s1);
#pragma unroll
  for (int off = 32; off; off >>= 1) m = fmaxf(m, __shfl_xor(m, off));
  const int wv = tid >> 6;
  if ((tid & 63) == 0) redm[wv] = m;
  __syncthreads();
  m = fmaxf(fmaxf(redm[0], redm[1]), fmaxf(redm[2], redm[3]));
  const float e0 = __builtin_amdgcn_exp2f((s0 - m) * LOG2E);
  const float e1 = __builtin_amdgcn_exp2f((s1 - m) * LOG2E);
  float sum = e0 + e1;
#pragma unroll
  for (int off = 32; off; off >>= 1) sum += __shfl_xor(sum, off);
  if ((tid & 63) == 0) reds[wv] = sum;
  __syncthreads();
  sum = reds[0] + reds[1] + reds[2] + reds[3];
  const float inv = 1.f / sum;
  w[tid] = e0 * inv;
  w[tid + 256] = e1 * inv;
  __syncthreads();

  const int h0 = (tid & 127) * 8;
  const int sh = tid >> 7;  // 0..1
  float a[8];
#pragma unroll
  for (int i = 0; i < 8; ++i) a[i] = 0.f;
  const size_t base = ((size_t)(b * 512 + scn * 128 + sh)) * 1024 + h0;
#pragma unroll 4
  for (int i = 0; i < 64; ++i) {
    const float ws_ = w[scn * 128 + sh + 2 * i];
    if constexpr (ABF16) {
      const uint4 v = *(const uint4*)((const unsigned short*)encv + base + (size_t)(2 * i) * 1024);
      a[0] += ws_ * bflo(v.x); a[1] += ws_ * bfhi(v.x);
      a[2] += ws_ * bflo(v.y); a[3] += ws_ * bfhi(v.y);
      a[4] += ws_ * bflo(v.z); a[5] += ws_ * bfhi(v.z);
      a[6] += ws_ * bflo(v.w); a[7] += ws_ * bfhi(v.w);
    } else {
      const float* ep = (const float*)encv + base + (size_t)(2 * i) * 1024;
      const float4 v0 = *(const float4*)ep;
      const float4 v1 = *(const float4*)(ep + 4);
      a[0] += ws_ * v0.x; a[1] += ws_ * v0.y;
      a[2] += ws_ * v0.z; a[3] += ws_ * v0.w;
      a[4] += ws_ * v1.x; a[5] += ws_ * v1.y;
      a[6] += ws_ * v1.z; a[7] += ws_ * v1.w;
    }
  }
#pragma unroll
  for (int i = 0; i < 8; ++i)
    atomicAdd(&att[(size_t)b * 1024 + h0 + i], a[i]);
}

// ---------------------------------------------------------------------------
// 5) GRU gemms. grid = (48 gi + 48 gh N-tiles of 64) x 4 K-quarters = 384.
// ---------------------------------------------------------------------------
__global__ __launch_bounds__(256) void k_gru_gemm(
    const float* __restrict__ xin,    // [64][1024]
    const float* __restrict__ att,    // [64][1024]
    const float* __restrict__ states, // [64][1024]
    const float* __restrict__ W_ih,   // [3072][2048]
    const float* __restrict__ W_hh,   // [3072][1024]
    float* __restrict__ gbuf) {       // [2][64][3072], pre-zeroed
  const int tid = threadIdx.x;
  const int wave = tid >> 6, lane = tid & 63;
  const int l15 = lane & 15, quad = lane >> 4;
  const int kk = blockIdx.x & 3;
  const int rest = blockIdx.x >> 2;   // 0..95
  const bool is_gh = rest >= 48;
  const int nt = is_gh ? rest - 48 : rest;
  const int n0 = nt * 64;
  const int KT = is_gh ? 1024 : 2048;
  const int Kh = KT >> 2;
  const int kbase = kk * Kh;
  const float* W = is_gh ? W_hh : W_ih;
  float* outp = gbuf + (is_gh ? (size_t)64 * 3072 : 0);

  __shared__ alignas(16) unsigned short lA[64 * LSTR];
  __shared__ alignas(16) unsigned short lB[64 * LSTR];

  const f32x4 vz = {0.f, 0.f, 0.f, 0.f};
  f32x4 acc[2][2];
  acc[0][0] = vz; acc[0][1] = vz; acc[1][0] = vz; acc[1][1] = vz;

  const int arow = tid >> 2;          // 0..63
  const int achunk = (tid & 3) * 8;
  const int wm2 = (wave >> 1) * 32, wn2 = (wave & 1) * 32;

#pragma unroll 1
  for (int k0 = 0; k0 < Kh; k0 += 32) {
    const int kg = kbase + k0 + achunk;
    const float* ap = is_gh ? (states + (size_t)arow * 1024 + kg)
                    : (kg < 1024 ? (xin + (size_t)arow * 1024 + kg)
                                 : (att + (size_t)arow * 1024 + (kg - 1024)));
    const ushort4 a0 = cvt4(*(const float4*)ap);
    const ushort4 a1 = cvt4(*(const float4*)(ap + 4));
    const float* wp = W + (size_t)(n0 + arow) * KT + kg;
    const ushort4 b0 = cvt4(*(const float4*)wp);
    const ushort4 b1 = cvt4(*(const float4*)(wp + 4));
    __syncthreads();
    *(ushort4*)(lA + arow * LSTR + achunk) = a0;
    *(ushort4*)(lA + arow * LSTR + achunk + 4) = a1;
    *(ushort4*)(lB + arow * LSTR + achunk) = b0;
    *(ushort4*)(lB + arow * LSTR + achunk + 4) = b1;
    __syncthreads();
    bf16x8 af[2], bg[2];
#pragma unroll
    for (int i = 0; i < 2; ++i)
      af[i] = *(const bf16x8*)(lA + (wm2 + i * 16 + l15) * LSTR + quad * 8);
#pragma unroll
    for (int j = 0; j < 2; ++j)
      bg[j] = *(const bf16x8*)(lB + (wn2 + j * 16 + l15) * LSTR + quad * 8);
#pragma unroll
    for (int i = 0; i < 2; ++i)
#pragma unroll
      for (int j = 0; j < 2; ++j)
        acc[i][j] = __builtin_amdgcn_mfma_f32_16x16x32_bf16(af[i], bg[j],
                                                            acc[i][j], 0, 0, 0);
  }
#pragma unroll
  for (int i = 0; i < 2; ++i)
#pragma unroll
    for (int j = 0; j < 2; ++j)
#pragma unroll
      for (int r = 0; r < 4; ++r) {
        const int m = wm2 + i * 16 + quad * 4 + r;
        const int n = n0 + wn2 + j * 16 + l15;
        atomicAdd(&outp[(size_t)m * 3072 + n], acc[i][j][r]);
      }
}

// ---------------------------------------------------------------------------
// 6) gates -> output fp32
// ---------------------------------------------------------------------------
__global__ void k_gate(const float* __restrict__ gbuf,
                       const float* __restrict__ states,
                       const float* __restrict__ b_ih,
                       const float* __restrict__ b_hh,
                       float* __restrict__ outp) {
  const int idx = blockIdx.x * 256 + threadIdx.x;  // 0..65535
  const int b = idx >> 10, h = idx & 1023;
  const float* gi = gbuf + (size_t)b * 3072;
  const float* gh = gbuf + (size_t)64 * 3072 + (size_t)b * 3072;
  const float ir = gi[h] + b_ih[h];
  const float iz = gi[1024 + h] + b_ih[1024 + h];
  const float in_ = gi[2048 + h] + b_ih[2048 + h];
  const float hr = gh[h] + b_hh[h];
  const float hz = gh[1024 + h] + b_hh[1024 + h];
  const float hn = gh[2048 + h] + b_hh[2048 + h];
  const float r = sigmoid_fast(ir + hr);
  const float z = sigmoid_fast(iz + hz);
  const float n = tanh_fast(in_ + r * hn);
  const float hp = states[idx];
  outp[idx] = (1.f - z) * n + z * hp;
}

// ---------------------------------------------------------------------------
extern "C" void kernel_launch(void* const* d_in, const int* in_sizes, int n_in,
                              void* d_out, int out_size, void* d_ws, size_t ws_size,
                              hipStream_t stream) {
  const float* enc    = (const float*)d_in[0];
  const float* xin    = (const float*)d_in[1];
  const float* states = (const float*)d_in[2];
  const float* W_enc  = (const float*)d_in[3];
  const float* b_enc  = (const float*)d_in[4];
  const float* W_dec  = (const float*)d_in[5];
  const float* b_dec  = (const float*)d_in[6];
  const float* w_out  = (const float*)d_in[7];
  // d_in[8] = b_out: softmax-shift-invariant, unused exactly.
  const float* W_ih   = (const float*)d_in[9];
  const float* W_hh   = (const float*)d_in[10];
  const float* b_ih   = (const float*)d_in[11];
  const float* b_hh   = (const float*)d_in[12];
  float* out = (float*)d_out;

  const size_t ENC_BF16_BYTES = (size_t)32768 * 1024 * 2;  // 64 MB
  const bool use_bf16 = ws_size >= ENC_BF16_BYTES + (8u << 20);

  char* ws = (char*)d_ws;
  unsigned short* encb = (unsigned short*)ws;              // 64 MB (bf16), optional
  char* base = ws + (use_bf16 ? ENC_BF16_BYTES : 0);
  unsigned short* Wt = (unsigned short*)base;              // 2 MB (bf16)
  float* dvec    = (float*)(base + 2097152);               // 256 KB
  // zero-region (contiguous): scoresb 128K | att 256K | gbuf 1.5M = 1.92 MB
  float* scoresb = (float*)(base + 2097152 + 262144);
  float* att     = (float*)(base + 2097152 + 262144 + 131072);
  float* gbuf    = (float*)(base + 2097152 + 262144 + 131072 + 262144);

  const int prep_grid = use_bf16 ? 17632 : 1248;
  k_prep<<<prep_grid, 256, 0, stream>>>(W_enc, Wt, states, W_dec, b_dec, b_enc,
                                        dvec, (float4*)scoresb, enc, encb);
  if (use_bf16) {
    k_scores_bf16<<<1024, 256, 0, stream>>>(encb, Wt, dvec, w_out, scoresb);
    k_attn<true><<<256, 256, 0, stream>>>(encb, scoresb, att);
  } else {
    k_scores_f32<<<1024, 256, 0, stream>>>(enc, Wt, dvec, w_out, scoresb);
    k_attn<false><<<256, 256, 0, stream>>>(enc, scoresb, att);
  }
  k_gru_gemm<<<384, 256, 0, stream>>>(xin, att, states, W_ih, W_hh, gbuf);
  k_gate<<<256, 256, 0, stream>>>(gbuf, states, b_ih, b_hh, out);
}

// Round 7
// 481.874 us; speedup vs baseline: 2.1366x; 2.1366x over previous
//
#include <hip/hip_runtime.h>
#include <stdint.h>

typedef __bf16 bf16x8 __attribute__((ext_vector_type(8)));
typedef float f32x4 __attribute__((ext_vector_type(4)));

#define LOG2E 1.4426950408889634f
#define LSTR 32  // LDS row stride in shorts (64 B); required by global_load_lds scatter

__device__ __forceinline__ unsigned short f2bf(float f) {
  unsigned int x = __builtin_bit_cast(unsigned int, f);
  x += 0x7FFFu + ((x >> 16) & 1u);
  return (unsigned short)(x >> 16);
}
__device__ __forceinline__ float bflo(unsigned int u) {
  return __builtin_bit_cast(float, u << 16);
}
__device__ __forceinline__ float bfhi(unsigned int u) {
  return __builtin_bit_cast(float, u & 0xffff0000u);
}
__device__ __forceinline__ float tanh_fast(float x) {
  float cx = fminf(fmaxf(x, -15.f), 15.f);
  float e = __builtin_amdgcn_exp2f(cx * (2.f * LOG2E));   // e^(2x)
  return (e - 1.f) * __builtin_amdgcn_rcpf(e + 1.f);
}
__device__ __forceinline__ float sigmoid_fast(float x) {
  float cx = fminf(fmaxf(x, -30.f), 30.f);
  float e = __builtin_amdgcn_exp2f(cx * LOG2E);           // e^x
  return e * __builtin_amdgcn_rcpf(e + 1.f);
}
__device__ __forceinline__ ushort4 cvt4(const float4 f) {
  return make_ushort4(f2bf(f.x), f2bf(f.y), f2bf(f.z), f2bf(f.w));
}

// async global->LDS, 16B/lane; LDS dest = wave-uniform base + lane*16.
__device__ __forceinline__ void gl_lds16(const unsigned short* g,
                                         const unsigned short* lds_base) {
  __builtin_amdgcn_global_load_lds(
      (const __attribute__((address_space(1))) unsigned int*)(uintptr_t)g,
      (__attribute__((address_space(3))) unsigned int*)(unsigned int)(uintptr_t)lds_base,
      16, 0, 0);
}

// ---------------------------------------------------------------------------
// 0) Fused prep: [0,256) W_enc transpose->bf16 | [256,768) dvec |
//    [768,1248) zero scoresb/att/gbuf | [1248,17632) enc fp32->bf16
// ---------------------------------------------------------------------------
__global__ __launch_bounds__(256) void k_prep(
    const float* __restrict__ W_enc, unsigned short* __restrict__ Wt,
    const float* __restrict__ states, const float* __restrict__ W_dec,
    const float* __restrict__ b_dec, const float* __restrict__ b_enc,
    float* __restrict__ dvec, float4* __restrict__ zbase,
    const float* __restrict__ enc, unsigned short* __restrict__ encb) {
  __shared__ unsigned short tile[64][65];
  __shared__ float red[256];
  const int bid = blockIdx.x;
  const int tid = threadIdx.x;
  if (bid < 256) {            // ---- transpose W_enc -> Wt (bf16)
    const int bx = bid & 15, by = bid >> 4;
    const int x = tid & 63, y0 = tid >> 6;
#pragma unroll
    for (int i = y0; i < 64; i += 4)
      tile[i][x] = f2bf(W_enc[(size_t)(by * 64 + i) * 1024 + bx * 64 + x]);
    __syncthreads();
#pragma unroll
    for (int i = y0; i < 64; i += 4)
      Wt[(size_t)(bx * 64 + i) * 1024 + by * 64 + x] = tile[x][i];
  } else if (bid < 768) {     // ---- dvec
    const int bb = bid - 256;
    const int b = bb >> 3;
    const int a0 = (bb & 7) * 128;
    const int a = tid & 127, half = tid >> 7;
    const float* sp = states + (size_t)b * 1024;
    const float* wp = W_dec + a0 + a;
    float acc = 0.f;
    const int kb = half * 512;
#pragma unroll 8
    for (int k = kb; k < kb + 512; ++k)
      acc += sp[k] * wp[(size_t)k * 1024];
    red[tid] = acc;
    __syncthreads();
    if (tid < 128) {
      float v = red[tid] + red[tid + 128];
      dvec[(size_t)b * 1024 + a0 + tid] = v + b_dec[a0 + tid] + b_enc[a0 + tid];
    }
  } else if (bid < 1248) {    // ---- zero 1.92 MB (scoresb|att|gbuf)
    const float4 z = {0.f, 0.f, 0.f, 0.f};
    zbase[(size_t)(bid - 768) * 256 + tid] = z;
  } else {                    // ---- enc fp32 -> bf16
    const size_t i = ((size_t)(bid - 1248) * 256 + tid) * 8;
    const float4 f0 = *(const float4*)(enc + i);
    const float4 f1 = *(const float4*)(enc + i + 4);
    *(ushort4*)(encb + i) = cvt4(f0);
    *(ushort4*)(encb + i + 4) = cvt4(f1);
  }
}

// ---------------------------------------------------------------------------
// 3a) Fused scores, bf16 fast path. Grid = 256 M-tiles x 4 N-halves = 1024.
//     Both N-tiles of the half processed in ONE K-sweep; all acc indexing
//     compile-time (epilogue fully unrolled — runtime index spills to scratch,
//     round-6 post-mortem: 4.29 GB HBM writes).
// ---------------------------------------------------------------------------
__global__ __launch_bounds__(256) void k_scores_bf16(
    const unsigned short* __restrict__ encb,  // [32768][1024] bf16
    const unsigned short* __restrict__ Wt,    // [1024 a][1024 h] bf16
    const float* __restrict__ dvec,           // [64][1024]
    const float* __restrict__ w_out,          // [1024]
    float* __restrict__ scores) {             // [64][512], pre-zeroed
  __shared__ alignas(16) unsigned short lA[128 * LSTR];       // 8 KB
  __shared__ alignas(16) unsigned short lB[2 * 128 * LSTR];   // 16 KB
  __shared__ float sc[128];

  const int tid = threadIdx.x;
  const int wave = tid >> 6, lane = tid & 63;
  const int l15 = lane & 15, quad = lane >> 4;
  const int mt = blockIdx.x >> 2;
  const int nh = blockIdx.x & 3;
  const int row0 = mt * 128;
  const int b = row0 >> 9;
  const int wm = (wave >> 1) * 64, wn = (wave & 1) * 64;
  const int srow = lane >> 2;         // 0..15 within staging region
  const int skoff = (lane & 3) * 8;   // k element offset of 8-elem chunk

  if (tid < 128) sc[tid] = 0.f;

  const f32x4 vz = {0.f, 0.f, 0.f, 0.f};
  f32x4 acc[2][4][4];
#pragma unroll
  for (int t = 0; t < 2; ++t)
#pragma unroll
    for (int i = 0; i < 4; ++i)
#pragma unroll
      for (int j = 0; j < 4; ++j) acc[t][i][j] = vz;

#pragma unroll 1
  for (int k0 = 0; k0 < 1024; k0 += 32) {
    __syncthreads();   // prev iteration's LDS reads done
#pragma unroll
    for (int s = 0; s < 6; ++s) {   // 24 regions / 4 waves
      const int g = wave * 6 + s;
      if (g < 8) {
        gl_lds16(encb + (size_t)(row0 + g * 16 + srow) * 1024 + k0 + skoff,
                 lA + g * 512);
      } else {
        const int t = (g - 8) >> 3;        // which nt
        const int q = (g - 8) & 7;         // region within nt's B tile
        gl_lds16(Wt + (size_t)((nh * 2 + t) * 128 + q * 16 + srow) * 1024 + k0 + skoff,
                 lB + t * 4096 + q * 512);
      }
    }
    __syncthreads();   // DMA drained
    bf16x8 af[4], bg[2][4];
#pragma unroll
    for (int i = 0; i < 4; ++i)
      af[i] = *(const bf16x8*)(lA + (wm + i * 16 + l15) * LSTR + quad * 8);
#pragma unroll
    for (int t = 0; t < 2; ++t)
#pragma unroll
      for (int j = 0; j < 4; ++j)
        bg[t][j] = *(const bf16x8*)(lB + t * 4096 + (wn + j * 16 + l15) * LSTR + quad * 8);
#pragma unroll
    for (int t = 0; t < 2; ++t)
#pragma unroll
      for (int i = 0; i < 4; ++i)
#pragma unroll
        for (int j = 0; j < 4; ++j)
          acc[t][i][j] = __builtin_amdgcn_mfma_f32_16x16x32_bf16(af[i], bg[t][j],
                                                                 acc[t][i][j], 0, 0, 0);
  }

  // Epilogue: FULLY unrolled (compile-time acc indexing only!)
#pragma unroll
  for (int t = 0; t < 2; ++t) {
    const int nt = nh * 2 + t;
    float p[4][4];
#pragma unroll
    for (int i = 0; i < 4; ++i)
#pragma unroll
      for (int r = 0; r < 4; ++r) p[i][r] = 0.f;
#pragma unroll
    for (int j = 0; j < 4; ++j) {
      const int a = nt * 128 + wn + j * 16 + l15;
      const float dv = dvec[(size_t)b * 1024 + a];
      const float wo = w_out[a];
#pragma unroll
      for (int i = 0; i < 4; ++i)
#pragma unroll
        for (int r = 0; r < 4; ++r)
          p[i][r] += tanh_fast(acc[t][i][j][r] + dv) * wo;
    }
#pragma unroll
    for (int i = 0; i < 4; ++i)
#pragma unroll
      for (int r = 0; r < 4; ++r) {
        float v = p[i][r];
        v += __shfl_xor(v, 1);
        v += __shfl_xor(v, 2);
        v += __shfl_xor(v, 4);
        v += __shfl_xor(v, 8);
        if (l15 == 0) atomicAdd(&sc[wm + i * 16 + quad * 4 + r], v);
      }
  }
  __syncthreads();
  if (tid < 128)
    atomicAdd(&scores[(size_t)b * 512 + (row0 & 511) + tid], sc[tid]);
}

// ---------------------------------------------------------------------------
// 3b) fp32 fallback (round-5 structure, manual staging)
// ---------------------------------------------------------------------------
__global__ __launch_bounds__(256) void k_scores_f32(
    const float* __restrict__ enc, const unsigned short* __restrict__ Wt,
    const float* __restrict__ dvec, const float* __restrict__ w_out,
    float* __restrict__ scores) {
  __shared__ alignas(16) unsigned short lA[128 * LSTR];
  __shared__ alignas(16) unsigned short lB[128 * LSTR];
  __shared__ float sc[128];
  const int tid = threadIdx.x;
  const int wave = tid >> 6, lane = tid & 63;
  const int l15 = lane & 15, quad = lane >> 4;
  const int mt = blockIdx.x >> 2, nh = blockIdx.x & 3;
  const int row0 = mt * 128, b = row0 >> 9;
  const int wm = (wave >> 1) * 64, wn = (wave & 1) * 64;
  const int srow = lane >> 2, skoff = (lane & 3) * 8;
  if (tid < 128) sc[tid] = 0.f;
  const f32x4 vz = {0.f, 0.f, 0.f, 0.f};
#pragma unroll 1
  for (int t2 = 0; t2 < 2; ++t2) {
    const int nt = nh * 2 + t2;
    f32x4 acc[4][4];
#pragma unroll
    for (int i = 0; i < 4; ++i)
#pragma unroll
      for (int j = 0; j < 4; ++j) acc[i][j] = vz;
#pragma unroll 1
    for (int k0 = 0; k0 < 1024; k0 += 32) {
      ushort4 sa[2][2];
      uint4 vb[2];
#pragma unroll
      for (int rr = 0; rr < 2; ++rr) {
        const int r = wave * 2 + rr;
        const float* ap = enc + (size_t)(row0 + r * 16 + srow) * 1024 + k0 + skoff;
        sa[rr][0] = cvt4(*(const float4*)ap);
        sa[rr][1] = cvt4(*(const float4*)(ap + 4));
        vb[rr] = *(const uint4*)(Wt + (size_t)(nt * 128 + r * 16 + srow) * 1024 + k0 + skoff);
      }
      __syncthreads();
#pragma unroll
      for (int rr = 0; rr < 2; ++rr) {
        const int r = wave * 2 + rr;
        *(ushort4*)(lA + (r * 16 + srow) * LSTR + skoff) = sa[rr][0];
        *(ushort4*)(lA + (r * 16 + srow) * LSTR + skoff + 4) = sa[rr][1];
        *(uint4*)(lB + (r * 16 + srow) * LSTR + skoff) = vb[rr];
      }
      __syncthreads();
      bf16x8 af[4], bg[4];
#pragma unroll
      for (int i = 0; i < 4; ++i)
        af[i] = *(const bf16x8*)(lA + (wm + i * 16 + l15) * LSTR + quad * 8);
#pragma unroll
      for (int j = 0; j < 4; ++j)
        bg[j] = *(const bf16x8*)(lB + (wn + j * 16 + l15) * LSTR + quad * 8);
#pragma unroll
      for (int i = 0; i < 4; ++i)
#pragma unroll
        for (int j = 0; j < 4; ++j)
          acc[i][j] = __builtin_amdgcn_mfma_f32_16x16x32_bf16(af[i], bg[j],
                                                              acc[i][j], 0, 0, 0);
    }
    float p[4][4];
#pragma unroll
    for (int i = 0; i < 4; ++i)
#pragma unroll
      for (int r = 0; r < 4; ++r) p[i][r] = 0.f;
#pragma unroll
    for (int j = 0; j < 4; ++j) {
      const int a = nt * 128 + wn + j * 16 + l15;
      const float dv = dvec[(size_t)b * 1024 + a];
      const float wo = w_out[a];
#pragma unroll
      for (int i = 0; i < 4; ++i)
#pragma unroll
        for (int r = 0; r < 4; ++r)
          p[i][r] += tanh_fast(acc[i][j][r] + dv) * wo;
    }
#pragma unroll
    for (int i = 0; i < 4; ++i)
#pragma unroll
      for (int r = 0; r < 4; ++r) {
        float v = p[i][r];
        v += __shfl_xor(v, 1);
        v += __shfl_xor(v, 2);
        v += __shfl_xor(v, 4);
        v += __shfl_xor(v, 8);
        if (l15 == 0) atomicAdd(&sc[wm + i * 16 + quad * 4 + r], v);
      }
  }
  __syncthreads();
  if (tid < 128)
    atomicAdd(&scores[(size_t)b * 512 + (row0 & 511) + tid], sc[tid]);
}

// ---------------------------------------------------------------------------
// 4) softmax over S + weighted sum of encoded -> att (fp32, atomic)
// ---------------------------------------------------------------------------
template <bool ABF16>
__global__ __launch_bounds__(256) void k_attn(const void* __restrict__ encv,
                                              const float* __restrict__ scores,
                                              float* __restrict__ att) {
  const int b = blockIdx.x >> 2;
  const int scn = blockIdx.x & 3;
  const int tid = threadIdx.x;
  __shared__ float w[512];
  __shared__ float redm[4], reds[4];

  const float s0 = scores[(size_t)b * 512 + tid];
  const float s1 = scores[(size_t)b * 512 + 256 + tid];
  float m = fmaxf(s0, s1);
#pragma unroll
  for (int off = 32; off; off >>= 1) m = fmaxf(m, __shfl_xor(m, off));
  const int wv = tid >> 6;
  if ((tid & 63) == 0) redm[wv] = m;
  __syncthreads();
  m = fmaxf(fmaxf(redm[0], redm[1]), fmaxf(redm[2], redm[3]));
  const float e0 = __builtin_amdgcn_exp2f((s0 - m) * LOG2E);
  const float e1 = __builtin_amdgcn_exp2f((s1 - m) * LOG2E);
  float sum = e0 + e1;
#pragma unroll
  for (int off = 32; off; off >>= 1) sum += __shfl_xor(sum, off);
  if ((tid & 63) == 0) reds[wv] = sum;
  __syncthreads();
  sum = reds[0] + reds[1] + reds[2] + reds[3];
  const float inv = 1.f / sum;
  w[tid] = e0 * inv;
  w[tid + 256] = e1 * inv;
  __syncthreads();

  const int h0 = (tid & 127) * 8;
  const int sh = tid >> 7;  // 0..1
  float a[8];
#pragma unroll
  for (int i = 0; i < 8; ++i) a[i] = 0.f;
  const size_t base = ((size_t)(b * 512 + scn * 128 + sh)) * 1024 + h0;
#pragma unroll 4
  for (int i = 0; i < 64; ++i) {
    const float ws_ = w[scn * 128 + sh + 2 * i];
    if constexpr (ABF16) {
      const uint4 v = *(const uint4*)((const unsigned short*)encv + base + (size_t)(2 * i) * 1024);
      a[0] += ws_ * bflo(v.x); a[1] += ws_ * bfhi(v.x);
      a[2] += ws_ * bflo(v.y); a[3] += ws_ * bfhi(v.y);
      a[4] += ws_ * bflo(v.z); a[5] += ws_ * bfhi(v.z);
      a[6] += ws_ * bflo(v.w); a[7] += ws_ * bfhi(v.w);
    } else {
      const float* ep = (const float*)encv + base + (size_t)(2 * i) * 1024;
      const float4 v0 = *(const float4*)ep;
      const float4 v1 = *(const float4*)(ep + 4);
      a[0] += ws_ * v0.x; a[1] += ws_ * v0.y;
      a[2] += ws_ * v0.z; a[3] += ws_ * v0.w;
      a[4] += ws_ * v1.x; a[5] += ws_ * v1.y;
      a[6] += ws_ * v1.z; a[7] += ws_ * v1.w;
    }
  }
#pragma unroll
  for (int i = 0; i < 8; ++i)
    atomicAdd(&att[(size_t)b * 1024 + h0 + i], a[i]);
}

// ---------------------------------------------------------------------------
// 5) GRU gemms. grid = (48 gi + 48 gh N-tiles of 64) x 4 K-quarters = 384.
// ---------------------------------------------------------------------------
__global__ __launch_bounds__(256) void k_gru_gemm(
    const float* __restrict__ xin,    // [64][1024]
    const float* __restrict__ att,    // [64][1024]
    const float* __restrict__ states, // [64][1024]
    const float* __restrict__ W_ih,   // [3072][2048]
    const float* __restrict__ W_hh,   // [3072][1024]
    float* __restrict__ gbuf) {       // [2][64][3072], pre-zeroed
  const int tid = threadIdx.x;
  const int wave = tid >> 6, lane = tid & 63;
  const int l15 = lane & 15, quad = lane >> 4;
  const int kk = blockIdx.x & 3;
  const int rest = blockIdx.x >> 2;   // 0..95
  const bool is_gh = rest >= 48;
  const int nt = is_gh ? rest - 48 : rest;
  const int n0 = nt * 64;
  const int KT = is_gh ? 1024 : 2048;
  const int Kh = KT >> 2;
  const int kbase = kk * Kh;
  const float* W = is_gh ? W_hh : W_ih;
  float* outp = gbuf + (is_gh ? (size_t)64 * 3072 : 0);

  __shared__ alignas(16) unsigned short lA[64 * LSTR];
  __shared__ alignas(16) unsigned short lB[64 * LSTR];

  const f32x4 vz = {0.f, 0.f, 0.f, 0.f};
  f32x4 acc[2][2];
  acc[0][0] = vz; acc[0][1] = vz; acc[1][0] = vz; acc[1][1] = vz;

  const int arow = tid >> 2;          // 0..63
  const int achunk = (tid & 3) * 8;
  const int wm2 = (wave >> 1) * 32, wn2 = (wave & 1) * 32;

#pragma unroll 1
  for (int k0 = 0; k0 < Kh; k0 += 32) {
    const int kg = kbase + k0 + achunk;
    const float* ap = is_gh ? (states + (size_t)arow * 1024 + kg)
                    : (kg < 1024 ? (xin + (size_t)arow * 1024 + kg)
                                 : (att + (size_t)arow * 1024 + (kg - 1024)));
    const ushort4 a0 = cvt4(*(const float4*)ap);
    const ushort4 a1 = cvt4(*(const float4*)(ap + 4));
    const float* wp = W + (size_t)(n0 + arow) * KT + kg;
    const ushort4 b0 = cvt4(*(const float4*)wp);
    const ushort4 b1 = cvt4(*(const float4*)(wp + 4));
    __syncthreads();
    *(ushort4*)(lA + arow * LSTR + achunk) = a0;
    *(ushort4*)(lA + arow * LSTR + achunk + 4) = a1;
    *(ushort4*)(lB + arow * LSTR + achunk) = b0;
    *(ushort4*)(lB + arow * LSTR + achunk + 4) = b1;
    __syncthreads();
    bf16x8 af[2], bg[2];
#pragma unroll
    for (int i = 0; i < 2; ++i)
      af[i] = *(const bf16x8*)(lA + (wm2 + i * 16 + l15) * LSTR + quad * 8);
#pragma unroll
    for (int j = 0; j < 2; ++j)
      bg[j] = *(const bf16x8*)(lB + (wn2 + j * 16 + l15) * LSTR + quad * 8);
#pragma unroll
    for (int i = 0; i < 2; ++i)
#pragma unroll
      for (int j = 0; j < 2; ++j)
        acc[i][j] = __builtin_amdgcn_mfma_f32_16x16x32_bf16(af[i], bg[j],
                                                            acc[i][j], 0, 0, 0);
  }
#pragma unroll
  for (int i = 0; i < 2; ++i)
#pragma unroll
    for (int j = 0; j < 2; ++j)
#pragma unroll
      for (int r = 0; r < 4; ++r) {
        const int m = wm2 + i * 16 + quad * 4 + r;
        const int n = n0 + wn2 + j * 16 + l15;
        atomicAdd(&outp[(size_t)m * 3072 + n], acc[i][j][r]);
      }
}

// ---------------------------------------------------------------------------
// 6) gates -> output fp32
// ---------------------------------------------------------------------------
__global__ void k_gate(const float* __restrict__ gbuf,
                       const float* __restrict__ states,
                       const float* __restrict__ b_ih,
                       const float* __restrict__ b_hh,
                       float* __restrict__ outp) {
  const int idx = blockIdx.x * 256 + threadIdx.x;  // 0..65535
  const int b = idx >> 10, h = idx & 1023;
  const float* gi = gbuf + (size_t)b * 3072;
  const float* gh = gbuf + (size_t)64 * 3072 + (size_t)b * 3072;
  const float ir = gi[h] + b_ih[h];
  const float iz = gi[1024 + h] + b_ih[1024 + h];
  const float in_ = gi[2048 + h] + b_ih[2048 + h];
  const float hr = gh[h] + b_hh[h];
  const float hz = gh[1024 + h] + b_hh[1024 + h];
  const float hn = gh[2048 + h] + b_hh[2048 + h];
  const float r = sigmoid_fast(ir + hr);
  const float z = sigmoid_fast(iz + hz);
  const float n = tanh_fast(in_ + r * hn);
  const float hp = states[idx];
  outp[idx] = (1.f - z) * n + z * hp;
}

// ---------------------------------------------------------------------------
extern "C" void kernel_launch(void* const* d_in, const int* in_sizes, int n_in,
                              void* d_out, int out_size, void* d_ws, size_t ws_size,
                              hipStream_t stream) {
  const float* enc    = (const float*)d_in[0];
  const float* xin    = (const float*)d_in[1];
  const float* states = (const float*)d_in[2];
  const float* W_enc  = (const float*)d_in[3];
  const float* b_enc  = (const float*)d_in[4];
  const float* W_dec  = (const float*)d_in[5];
  const float* b_dec  = (const float*)d_in[6];
  const float* w_out  = (const float*)d_in[7];
  // d_in[8] = b_out: softmax-shift-invariant, unused exactly.
  const float* W_ih   = (const float*)d_in[9];
  const float* W_hh   = (const float*)d_in[10];
  const float* b_ih   = (const float*)d_in[11];
  const float* b_hh   = (const float*)d_in[12];
  float* out = (float*)d_out;

  const size_t ENC_BF16_BYTES = (size_t)32768 * 1024 * 2;  // 64 MB
  const bool use_bf16 = ws_size >= ENC_BF16_BYTES + (8u << 20);

  char* ws = (char*)d_ws;
  unsigned short* encb = (unsigned short*)ws;              // 64 MB (bf16), optional
  char* base = ws + (use_bf16 ? ENC_BF16_BYTES : 0);
  unsigned short* Wt = (unsigned short*)base;              // 2 MB (bf16)
  float* dvec    = (float*)(base + 2097152);               // 256 KB
  // zero-region (contiguous): scoresb 128K | att 256K | gbuf 1.5M = 1.92 MB
  float* scoresb = (float*)(base + 2097152 + 262144);
  float* att     = (float*)(base + 2097152 + 262144 + 131072);
  float* gbuf    = (float*)(base + 2097152 + 262144 + 131072 + 262144);

  const int prep_grid = use_bf16 ? 17632 : 1248;
  k_prep<<<prep_grid, 256, 0, stream>>>(W_enc, Wt, states, W_dec, b_dec, b_enc,
                                        dvec, (float4*)scoresb, enc, encb);
  if (use_bf16) {
    k_scores_bf16<<<1024, 256, 0, stream>>>(encb, Wt, dvec, w_out, scoresb);
    k_attn<true><<<256, 256, 0, stream>>>(encb, scoresb, att);
  } else {
    k_scores_f32<<<1024, 256, 0, stream>>>(enc, Wt, dvec, w_out, scoresb);
    k_attn<false><<<256, 256, 0, stream>>>(enc, scoresb, att);
  }
  k_gru_gemm<<<384, 256, 0, stream>>>(xin, att, states, W_ih, W_hh, gbuf);
  k_gate<<<256, 256, 0, stream>>>(gbuf, states, b_ih, b_hh, out);
}